// Round 1
// baseline (184.633 us; speedup 1.0000x reference)
//
#include <hip/hip_runtime.h>
#include <cstddef>

constexpr int NN  = 40000;   // nodes
constexpr int NE  = 640000;  // edges
constexpr int DIM = 128;     // D_IN == D_OUT
constexpr int CAP = 48;      // per-node neighbor capacity (max deg ~36 for Poisson(16))
constexpr int PLANE32   = NN * 32;  // shorts per 32-dim plane (2.56 MB -> fits 4MiB XCD L2)
constexpr int PLANE32_U = NN * 16;  // uints per 32-dim plane

typedef __attribute__((ext_vector_type(8))) short short8;   // 8 bf16 (4 VGPRs)
typedef __attribute__((ext_vector_type(4))) float floatx4;  // MFMA acc

// fp32 -> bf16 with round-to-nearest-even
__device__ __forceinline__ unsigned short f2bf(float x) {
    union { float f; unsigned int i; } v; v.f = x;
    unsigned int u = v.i;
    return (unsigned short)((u + 0x7fffu + ((u >> 16) & 1u)) >> 16);
}
__device__ __forceinline__ float bflo2f(unsigned int u) {   // low bf16 -> f32
    union { unsigned int i; float f; } v; v.i = u << 16; return v.f;
}
__device__ __forceinline__ float bfhi2f(unsigned int u) {   // high bf16 -> f32
    union { unsigned int i; float f; } v; v.i = u & 0xffff0000u; return v.f;
}

// ---------------------------------------------------------------------------
// Fused prep + fill (cnt pre-zeroed by hipMemsetAsync):
//   blocks    0..2499 : cast feat fp32 -> bf16 planes featb[4][NN][32]
//   blocks 2500..2627 : transpose+cast W to Wc[4][128][64]
//   blocks 2628..5127 : adjacency fill (atomicAdd cnt, scatter colf)
// Cast traffic overlaps the atomic/scatter-bound fill inside one dispatch.
// ---------------------------------------------------------------------------
__global__ __launch_bounds__(256) void k_prep_fill(
    const float* __restrict__ feat, const float* __restrict__ Wself,
    const float* __restrict__ Wneigh, const int* __restrict__ src,
    const int* __restrict__ dst, unsigned short* __restrict__ featb,
    unsigned short* __restrict__ Wc, int* __restrict__ cnt,
    unsigned short* __restrict__ colf)
{
    int b = blockIdx.x, t = threadIdx.x;
    if (b < 2500) {
        int idx8 = b * 256 + t;          // 640000 groups of 8 dims
        int n  = idx8 >> 4;              // 16 groups per row
        int d0 = (idx8 & 15) << 3;       // dim base 0,8,...,120
        const float4* fp =
            reinterpret_cast<const float4*>(feat + (size_t)n * DIM + d0);
        float4 v0 = fp[0], v1 = fp[1];
        unsigned int p0 = (unsigned int)f2bf(v0.x) | ((unsigned int)f2bf(v0.y) << 16);
        unsigned int p1 = (unsigned int)f2bf(v0.z) | ((unsigned int)f2bf(v0.w) << 16);
        unsigned int p2 = (unsigned int)f2bf(v1.x) | ((unsigned int)f2bf(v1.y) << 16);
        unsigned int p3 = (unsigned int)f2bf(v1.z) | ((unsigned int)f2bf(v1.w) << 16);
        int plane = d0 >> 5, off = d0 & 31;   // 32-dim planes now
        *reinterpret_cast<uint4*>(
            featb + (size_t)plane * PLANE32 + (size_t)n * 32 + off) =
            make_uint4(p0, p1, p2, p3);
    } else if (b < 2628) {
        int idx = (b - 2500) * 256 + t;  // 0..32767
        int c = idx >> 13, n = (idx >> 6) & 127, kp = idx & 63;
        int k = c * 64 + kp;
        float w = (k < DIM) ? Wself[(size_t)k * DIM + n]
                            : Wneigh[(size_t)(k - DIM) * DIM + n];
        Wc[idx] = f2bf(w);
    } else {
        int e = (b - 2628) * 256 + t;    // exactly 640000 threads
        int d = dst[e];
        int pos = atomicAdd(&cnt[d], 1);
        if (pos < CAP) colf[d * CAP + pos] = (unsigned short)src[e];
    }
}

// ---------------------------------------------------------------------------
// Gather + mean, v2: XCD-L2-resident planes.
//   grid = 40000 blocks x 4 waves; plane = blockIdx&3 (XCD round-robin pins
//   plane p to XCDs {p,p+4}: 2.56MB plane fits the 4MiB per-XCD L2).
//   Wave = 4 neighbor slots (j=lane>>4) x 16 dim-uints (u=lane&15):
//   each load instruction fetches 4 neighbor rows (4x64B); 8 edges/iter.
//   Final shfl_xor(16,32) reduces the 4 slots; lanes 0-15 write the mean.
// ---------------------------------------------------------------------------
__global__ __launch_bounds__(256) void k_gather(
    const unsigned int* __restrict__ fb32,   // featb viewed as [4][NN][16] uint
    const int* __restrict__ cnt,
    const unsigned short* __restrict__ colf,
    unsigned int* __restrict__ hnb32)        // hnb viewed as [4][NN][16] uint
{
    int g = blockIdx.x;
    int p = g & 3;                                    // plane / XCD class
    int n = ((g >> 2) << 2) + (threadIdx.x >> 6);     // node
    int lane = threadIdx.x & 63;
    int j = lane >> 4;                                // neighbor slot 0..3
    int u = lane & 15;                                // dim-uint 0..15

    int deg = cnt[n];
    int m = min(deg, CAP);
    int sv = (lane < m) ? (int)colf[n * CAP + lane] : 0;

    const unsigned int* pb = fb32 + (size_t)p * PLANE32_U;
    float ax = 0.f, ay = 0.f;
    for (int i = 0; i < m; i += 8) {
        int i0 = i + j, i1 = i + 4 + j;
        int s0 = __shfl(sv, i0);                      // idx>=m reads lane's 0 -> row 0 (masked)
        int s1 = __shfl(sv, i1);
        unsigned int v0 = pb[s0 * 16 + u];
        unsigned int v1 = pb[s1 * 16 + u];
        if (i0 < m) { ax += bflo2f(v0); ay += bfhi2f(v0); }
        if (i1 < m) { ax += bflo2f(v1); ay += bfhi2f(v1); }
    }
    // reduce across the 4 neighbor slots
    ax += __shfl_xor(ax, 16); ay += __shfl_xor(ay, 16);
    ax += __shfl_xor(ax, 32); ay += __shfl_xor(ay, 32);
    if (lane < 16) {
        float inv = 1.0f / fmaxf((float)deg, 1.0f);
        hnb32[(size_t)p * PLANE32_U + (size_t)n * 16 + u] =
            (unsigned int)f2bf(ax * inv) | ((unsigned int)f2bf(ay * inv) << 16);
    }
}

// ---------------------------------------------------------------------------
// Fused GEMM: out[40000x128] = [featb | hnb] (K=256 bf16) @ Wc + biases.
// 500 blocks x 80 rows (2 blocks/CU so barrier-drain staging stalls overlap
// across blocks); 5 waves; 16x16x32 bf16 MFMA; staging via global_load_lds
// width=16. A-source addresses adapted to 32-dim-plane layout (per-lane
// global address, linear LDS destination).
// ---------------------------------------------------------------------------
__global__ __launch_bounds__(320) void k_gemm(
    const unsigned short* __restrict__ featb,  // [4][NN][32]
    const unsigned short* __restrict__ hnb,    // [4][NN][32]
    const unsigned short* __restrict__ Wc,     // [4][128][64]
    const float* __restrict__ bself, const float* __restrict__ bneigh,
    float* __restrict__ out)                   // [NN,128] fp32
{
    __shared__ __align__(16) unsigned short As[80 * 64];   // 10240 B
    __shared__ __align__(16) unsigned short Bs[128 * 64];  // 16384 B

    int t = threadIdx.x;
    int w = t >> 6;
    int lane = t & 63;
    int base_m = blockIdx.x * 80;

    floatx4 acc[8];
    #pragma unroll
    for (int i = 0; i < 8; ++i) acc[i] = (floatx4)0.f;

    for (int c = 0; c < 4; ++c) {
        // ---- stage A chunk (80x64 = 10240 B): K rows c*64..c*64+63 ----
        const unsigned short* sp = (c < 2) ? featb : hnb;
        int cc = c & 1;                       // plane pair 2cc, 2cc+1
        #pragma unroll
        for (int it = 0; it < 2; ++it) {      // 640 slots / 320 threads
            int s = t + it * 320;
            int m = s >> 3, q = s & 7;        // kp = q*8
            const unsigned short* sa =
                sp + (size_t)(2 * cc + (q >> 2)) * PLANE32
                   + (size_t)(base_m + m) * 32 + (q & 3) * 8;
            __builtin_amdgcn_global_load_lds(
                (const __attribute__((address_space(1))) unsigned int*)sa,
                (__attribute__((address_space(3))) unsigned int*)(As + s * 8),
                16, 0, 0);
        }
        // ---- stage B chunk (16384 B): waves 0..3 ----
        if (t < 256) {
            const unsigned short* bp = Wc + (size_t)c * 8192;
            #pragma unroll
            for (int it = 0; it < 4; ++it) {  // 1024 slots / 256 threads
                int s = t + it * 256;
                __builtin_amdgcn_global_load_lds(
                    (const __attribute__((address_space(1))) unsigned int*)(bp + s * 8),
                    (__attribute__((address_space(3))) unsigned int*)(Bs + s * 8),
                    16, 0, 0);
            }
        }
        __syncthreads();

        // ---- 2 k-steps of 32 ----
        #pragma unroll
        for (int sstep = 0; sstep < 2; ++sstep) {
            int koff = sstep * 32 + (lane >> 4) * 8;
            short8 af = *reinterpret_cast<const short8*>(
                As + (w * 16 + (lane & 15)) * 64 + koff);
            #pragma unroll
            for (int nt = 0; nt < 8; ++nt) {
                short8 bf = *reinterpret_cast<const short8*>(
                    Bs + (nt * 16 + (lane & 15)) * 64 + koff);
                acc[nt] = __builtin_amdgcn_mfma_f32_16x16x32_bf16(
                    af, bf, acc[nt], 0, 0, 0);
            }
        }
        __syncthreads();
    }

    // ---- epilogue: C/D layout col=lane&15, row=(lane>>4)*4+reg ----
    int colb = lane & 15;
    int quad = lane >> 4;
    #pragma unroll
    for (int nt = 0; nt < 8; ++nt) {
        int col = nt * 16 + colb;
        float bb = bself[col] + bneigh[col];
        #pragma unroll
        for (int r = 0; r < 4; ++r) {
            int row = base_m + w * 16 + quad * 4 + r;
            out[(size_t)row * DIM + col] = acc[nt][r] + bb;
        }
    }
}

// ---------------------------------------------------------------------------
extern "C" void kernel_launch(void* const* d_in, const int* in_sizes, int n_in,
                              void* d_out, int out_size, void* d_ws, size_t ws_size,
                              hipStream_t stream)
{
    const float* feat   = (const float*)d_in[0];
    const int*   src    = (const int*)d_in[1];
    const int*   dst    = (const int*)d_in[2];
    const float* Wself  = (const float*)d_in[3];
    const float* bself  = (const float*)d_in[4];
    const float* Wneigh = (const float*)d_in[5];
    const float* bneigh = (const float*)d_in[6];
    float* out = (float*)d_out;

    // Workspace layout (bytes):
    //   featb [4][NN][32] bf16 @ 0           (10,240,000)
    //   hnb   [4][NN][32] bf16 @ 10,240,000  (10,240,000)
    //   colf  [NN][CAP]   u16  @ 20,480,000  ( 3,840,000)
    //   Wc    [4][128][64]bf16 @ 24,320,000  (    65,536)
    //   cnt   [NN]        i32  @ 24,385,536  (   160,000)
    // total 24,545,536 B
    char* ws = (char*)d_ws;
    unsigned short* featb = (unsigned short*)(ws);
    unsigned short* hnb   = (unsigned short*)(ws + 10240000);
    unsigned short* colf  = (unsigned short*)(ws + 20480000);
    unsigned short* Wc    = (unsigned short*)(ws + 24320000);
    int*            cnt   = (int*)(ws + 24385536);

    hipMemsetAsync(cnt, 0, NN * sizeof(int), stream);

    k_prep_fill<<<5128, 256, 0, stream>>>(
        feat, Wself, Wneigh, src, dst, featb, Wc, cnt, colf);

    k_gather<<<40000, 256, 0, stream>>>(
        (const unsigned int*)featb, cnt, colf, (unsigned int*)hnb);

    k_gemm<<<500, 320, 0, stream>>>(featb, hnb, Wc, bself, bneigh, out);
}

// Round 2
// 148.841 us; speedup vs baseline: 1.2405x; 1.2405x over previous
//
#include <hip/hip_runtime.h>
#include <cstddef>

constexpr int NN  = 40000;   // nodes
constexpr int NE  = 640000;  // edges
constexpr int DIM = 128;     // D_IN == D_OUT
constexpr int CAP = 48;      // per-node neighbor capacity (max deg ~36 for Poisson(16))
constexpr int PLANE = NN * 64;  // shorts per 64-dim plane

typedef __attribute__((ext_vector_type(8))) short short8;   // 8 bf16 (4 VGPRs)
typedef __attribute__((ext_vector_type(4))) float floatx4;  // MFMA acc

// fp32 -> bf16 with round-to-nearest-even
__device__ __forceinline__ unsigned short f2bf(float x) {
    union { float f; unsigned int i; } v; v.f = x;
    unsigned int u = v.i;
    return (unsigned short)((u + 0x7fffu + ((u >> 16) & 1u)) >> 16);
}
__device__ __forceinline__ float bflo2f(unsigned int u) {   // low bf16 -> f32
    union { unsigned int i; float f; } v; v.i = u << 16; return v.f;
}
__device__ __forceinline__ float bfhi2f(unsigned int u) {   // high bf16 -> f32
    union { unsigned int i; float f; } v; v.i = u & 0xffff0000u; return v.f;
}

// ---------------------------------------------------------------------------
// Prep: [blocks 0..2499] cast feat fp32 -> bf16 planes featb[2][NN][64]
//       [blocks 2500..2627] transpose+cast W to Wc[4][128][64]
//       [blocks 2628..2784] zero cnt[NN]
// (round-0 proven version; fusion with the fill regressed — r1 post-mortem)
// ---------------------------------------------------------------------------
__global__ __launch_bounds__(256) void k_prep(
    const float* __restrict__ feat, const float* __restrict__ Wself,
    const float* __restrict__ Wneigh, unsigned short* __restrict__ featb,
    unsigned short* __restrict__ Wc, int* __restrict__ cnt)
{
    int b = blockIdx.x, t = threadIdx.x;
    if (b < 2500) {
        int idx8 = b * 256 + t;          // 640000 groups of 8 elements
        int n  = idx8 >> 4;              // 16 groups per row
        int d0 = (idx8 & 15) << 3;       // dim base 0,8,...,120
        const float4* fp =
            reinterpret_cast<const float4*>(feat + (size_t)n * DIM + d0);
        float4 v0 = fp[0], v1 = fp[1];
        unsigned int p0 = (unsigned int)f2bf(v0.x) | ((unsigned int)f2bf(v0.y) << 16);
        unsigned int p1 = (unsigned int)f2bf(v0.z) | ((unsigned int)f2bf(v0.w) << 16);
        unsigned int p2 = (unsigned int)f2bf(v1.x) | ((unsigned int)f2bf(v1.y) << 16);
        unsigned int p3 = (unsigned int)f2bf(v1.z) | ((unsigned int)f2bf(v1.w) << 16);
        int plane = d0 >> 6, off = d0 & 63;
        *reinterpret_cast<uint4*>(
            featb + (size_t)plane * PLANE + (size_t)n * 64 + off) =
            make_uint4(p0, p1, p2, p3);
    } else if (b < 2628) {
        int idx = (b - 2500) * 256 + t;  // 0..32767
        int c = idx >> 13, n = (idx >> 6) & 127, kp = idx & 63;
        int k = c * 64 + kp;
        float w = (k < DIM) ? Wself[(size_t)k * DIM + n]
                            : Wneigh[(size_t)(k - DIM) * DIM + n];
        Wc[idx] = f2bf(w);
    } else {
        int i = (b - 2628) * 256 + t;
        if (i < NN) cnt[i] = 0;
    }
}

// ---------------------------------------------------------------------------
// Adjacency fill, v2: 4 independent atomic chains per thread.
// The atomic->store dependency (~600-900 cyc to the coherent point) was the
// stall in r1's counters (VALUBusy 1.3%, HBM 12%); 4-way MLP hides it.
// Loads stay coalesced (stride-160000 slices).
// ---------------------------------------------------------------------------
__global__ __launch_bounds__(256) void k_fill(
    const int* __restrict__ src, const int* __restrict__ dst,
    int* __restrict__ cnt, unsigned short* __restrict__ colf)
{
    int t0 = blockIdx.x * 256 + threadIdx.x;   // 0..159999
    int d[4], s[4], pos[4];
    #pragma unroll
    for (int k = 0; k < 4; ++k) {
        int e = t0 + k * 160000;
        d[k] = dst[e];
        s[k] = src[e];
    }
    #pragma unroll
    for (int k = 0; k < 4; ++k)
        pos[k] = atomicAdd(&cnt[d[k]], 1);
    #pragma unroll
    for (int k = 0; k < 4; ++k)
        if (pos[k] < CAP) colf[d[k] * CAP + pos[k]] = (unsigned short)s[k];
}

// ---------------------------------------------------------------------------
// Gather + mean over bf16 planes: one wave per node, lane covers 2 dims
// (one uint = 2 bf16 per row; lanes 0-31 plane 0, lanes 32-63 plane 1).
// v2: 8 independent row loads in flight (was 4) — halves the number of
// latency-exposed batches per node (deg~16 -> 2 batches).
// ---------------------------------------------------------------------------
__global__ __launch_bounds__(256) void k_gather(
    const unsigned int* __restrict__ fb32,   // featb viewed as [2][NN][32] uint
    const int* __restrict__ cnt,
    const unsigned short* __restrict__ colf,
    unsigned int* __restrict__ hnb32)        // hnb viewed as [2][NN][32] uint
{
    int gtid = blockIdx.x * blockDim.x + threadIdx.x;
    int n = gtid >> 6;
    if (n >= NN) return;
    int lane = threadIdx.x & 63;

    int deg = cnt[n];
    int m = min(deg, CAP);
    int sv = (lane < m) ? (int)colf[n * CAP + lane] : 0;

    int vb = (lane >> 5) * (NN * 32) + (lane & 31);   // plane base + lane offset
    float ax0 = 0.f, ay0 = 0.f, ax1 = 0.f, ay1 = 0.f;
    int i = 0;
    for (; i + 7 < m; i += 8) {
        int s0 = __shfl(sv, i),     s1 = __shfl(sv, i + 1);
        int s2 = __shfl(sv, i + 2), s3 = __shfl(sv, i + 3);
        int s4 = __shfl(sv, i + 4), s5 = __shfl(sv, i + 5);
        int s6 = __shfl(sv, i + 6), s7 = __shfl(sv, i + 7);
        unsigned int u0 = fb32[vb + s0 * 32];
        unsigned int u1 = fb32[vb + s1 * 32];
        unsigned int u2 = fb32[vb + s2 * 32];
        unsigned int u3 = fb32[vb + s3 * 32];
        unsigned int u4 = fb32[vb + s4 * 32];
        unsigned int u5 = fb32[vb + s5 * 32];
        unsigned int u6 = fb32[vb + s6 * 32];
        unsigned int u7 = fb32[vb + s7 * 32];
        ax0 += bflo2f(u0); ay0 += bfhi2f(u0);
        ax1 += bflo2f(u1); ay1 += bfhi2f(u1);
        ax0 += bflo2f(u2); ay0 += bfhi2f(u2);
        ax1 += bflo2f(u3); ay1 += bfhi2f(u3);
        ax0 += bflo2f(u4); ay0 += bfhi2f(u4);
        ax1 += bflo2f(u5); ay1 += bfhi2f(u5);
        ax0 += bflo2f(u6); ay0 += bfhi2f(u6);
        ax1 += bflo2f(u7); ay1 += bfhi2f(u7);
    }
    for (; i + 3 < m; i += 4) {
        int s0 = __shfl(sv, i),     s1 = __shfl(sv, i + 1);
        int s2 = __shfl(sv, i + 2), s3 = __shfl(sv, i + 3);
        unsigned int u0 = fb32[vb + s0 * 32];
        unsigned int u1 = fb32[vb + s1 * 32];
        unsigned int u2 = fb32[vb + s2 * 32];
        unsigned int u3 = fb32[vb + s3 * 32];
        ax0 += bflo2f(u0); ay0 += bfhi2f(u0);
        ax1 += bflo2f(u1); ay1 += bfhi2f(u1);
        ax0 += bflo2f(u2); ay0 += bfhi2f(u2);
        ax1 += bflo2f(u3); ay1 += bfhi2f(u3);
    }
    for (; i < m; ++i) {
        int s0 = __shfl(sv, i);
        unsigned int u0 = fb32[vb + s0 * 32];
        ax0 += bflo2f(u0); ay0 += bfhi2f(u0);
    }
    float inv = 1.0f / fmaxf((float)deg, 1.0f);
    float ax = (ax0 + ax1) * inv, ay = (ay0 + ay1) * inv;
    hnb32[vb + n * 32] = (unsigned int)f2bf(ax) | ((unsigned int)f2bf(ay) << 16);
}

// ---------------------------------------------------------------------------
// Fused GEMM: out[40000x128] = [featb | hnb] (K=256 bf16) @ Wc + biases.
// 250 blocks x 160 rows; 5 waves; 16x16x32 bf16 MFMA; all staging via
// global_load_lds width=16 (sources are contiguous bf16 planes).
// (round-0 proven version — r1's 80-row scattered-stage variant regressed)
// ---------------------------------------------------------------------------
__global__ __launch_bounds__(320) void k_gemm(
    const unsigned short* __restrict__ featb,  // [2][NN][64]
    const unsigned short* __restrict__ hnb,    // [2][NN][64]
    const unsigned short* __restrict__ Wc,     // [4][128][64]
    const float* __restrict__ bself, const float* __restrict__ bneigh,
    float* __restrict__ out)                   // [NN,128] fp32
{
    __shared__ unsigned short As[160 * 64];  // 20480 B
    __shared__ unsigned short Bs[128 * 64];  // 16384 B

    int t = threadIdx.x;
    int w = t >> 6;
    int lane = t & 63;
    int base_m = blockIdx.x * 160;

    floatx4 acc[2][8];
    #pragma unroll
    for (int a = 0; a < 2; ++a)
        #pragma unroll
        for (int b = 0; b < 8; ++b) acc[a][b] = (floatx4)0.f;

    for (int c = 0; c < 4; ++c) {
        // ---- stage A chunk (20480 B): plane c of featb (c<2) or hnb ----
        const unsigned short* srcp =
            ((c < 2) ? featb + (size_t)c * PLANE
                     : hnb + (size_t)(c - 2) * PLANE) + (size_t)base_m * 64;
        #pragma unroll
        for (int it = 0; it < 4; ++it) {          // 1280 slots / 320 threads
            int slot = t + it * 320;
            __builtin_amdgcn_global_load_lds(
                (const __attribute__((address_space(1))) unsigned int*)(srcp + slot * 8),
                (__attribute__((address_space(3))) unsigned int*)(As + slot * 8),
                16, 0, 0);
        }
        // ---- stage B chunk (16384 B): waves 0..3 ----
        if (t < 256) {
            const unsigned short* bp = Wc + (size_t)c * 128 * 64;
            #pragma unroll
            for (int it = 0; it < 4; ++it) {      // 1024 slots / 256 threads
                int slot = t + it * 256;
                __builtin_amdgcn_global_load_lds(
                    (const __attribute__((address_space(1))) unsigned int*)(bp + slot * 8),
                    (__attribute__((address_space(3))) unsigned int*)(Bs + slot * 8),
                    16, 0, 0);
            }
        }
        __syncthreads();

        // ---- 2 k-steps of 32 ----
        #pragma unroll
        for (int s = 0; s < 2; ++s) {
            int koff = s * 32 + (lane >> 4) * 8;
            short8 af[2];
            #pragma unroll
            for (int mt = 0; mt < 2; ++mt) {
                int m = w * 32 + mt * 16 + (lane & 15);
                af[mt] = *reinterpret_cast<const short8*>(As + m * 64 + koff);
            }
            #pragma unroll
            for (int nt = 0; nt < 8; ++nt) {
                int n = nt * 16 + (lane & 15);
                short8 bf = *reinterpret_cast<const short8*>(Bs + n * 64 + koff);
                acc[0][nt] = __builtin_amdgcn_mfma_f32_16x16x32_bf16(
                    af[0], bf, acc[0][nt], 0, 0, 0);
                acc[1][nt] = __builtin_amdgcn_mfma_f32_16x16x32_bf16(
                    af[1], bf, acc[1][nt], 0, 0, 0);
            }
        }
        __syncthreads();
    }

    // ---- epilogue: C/D layout col=lane&15, row=(lane>>4)*4+reg ----
    int colb = lane & 15;
    int quad = lane >> 4;
    #pragma unroll
    for (int nt = 0; nt < 8; ++nt) {
        int col = nt * 16 + colb;
        float bb = bself[col] + bneigh[col];
        #pragma unroll
        for (int mt = 0; mt < 2; ++mt) {
            #pragma unroll
            for (int r = 0; r < 4; ++r) {
                int row = base_m + w * 32 + mt * 16 + quad * 4 + r;
                out[(size_t)row * DIM + col] = acc[mt][nt][r] + bb;
            }
        }
    }
}

// ---------------------------------------------------------------------------
extern "C" void kernel_launch(void* const* d_in, const int* in_sizes, int n_in,
                              void* d_out, int out_size, void* d_ws, size_t ws_size,
                              hipStream_t stream)
{
    const float* feat   = (const float*)d_in[0];
    const int*   src    = (const int*)d_in[1];
    const int*   dst    = (const int*)d_in[2];
    const float* Wself  = (const float*)d_in[3];
    const float* bself  = (const float*)d_in[4];
    const float* Wneigh = (const float*)d_in[5];
    const float* bneigh = (const float*)d_in[6];
    float* out = (float*)d_out;

    // Workspace layout (bytes):
    //   featb [2][NN][64] bf16 @ 0           (10,240,000)
    //   hnb   [2][NN][64] bf16 @ 10,240,000  (10,240,000)
    //   colf  [NN][CAP]   u16  @ 20,480,000  ( 3,840,000)
    //   Wc    [4][128][64]bf16 @ 24,320,000  (    65,536)
    //   cnt   [NN]        i32  @ 24,385,536  (   160,000)
    // total 24,545,536 B
    char* ws = (char*)d_ws;
    unsigned short* featb = (unsigned short*)(ws);
    unsigned short* hnb   = (unsigned short*)(ws + 10240000);
    unsigned short* colf  = (unsigned short*)(ws + 20480000);
    unsigned short* Wc    = (unsigned short*)(ws + 24320000);
    int*            cnt   = (int*)(ws + 24385536);

    k_prep<<<2785, 256, 0, stream>>>(feat, Wself, Wneigh, featb, Wc, cnt);

    k_fill<<<625, 256, 0, stream>>>(src, dst, cnt, colf);

    k_gather<<<(NN * 64) / 256, 256, 0, stream>>>(
        (const unsigned int*)featb, cnt, colf, (unsigned int*)hnb);

    k_gemm<<<NN / 160, 320, 0, stream>>>(featb, hnb, Wc, bself, bneigh, out);
}

// Round 4
// 148.313 us; speedup vs baseline: 1.2449x; 1.0036x over previous
//
#include <hip/hip_runtime.h>
#include <cstddef>

constexpr int NN  = 40000;   // nodes
constexpr int NE  = 640000;  // edges
constexpr int DIM = 128;     // D_IN == D_OUT
constexpr int CAP = 48;      // per-node neighbor capacity (max deg ~36 for Poisson(16))
constexpr int PLANE = NN * 64;  // shorts per 64-dim plane

typedef __attribute__((ext_vector_type(8))) short short8;   // 8 bf16 (4 VGPRs)
typedef __attribute__((ext_vector_type(4))) float floatx4;  // MFMA acc
typedef __attribute__((ext_vector_type(4))) unsigned int uint32x4; // clang vector (nontemporal ok)

// fp32 -> bf16 with round-to-nearest-even
__device__ __forceinline__ unsigned short f2bf(float x) {
    union { float f; unsigned int i; } v; v.f = x;
    unsigned int u = v.i;
    return (unsigned short)((u + 0x7fffu + ((u >> 16) & 1u)) >> 16);
}
__device__ __forceinline__ float bflo2f(unsigned int u) {   // low bf16 -> f32
    union { unsigned int i; float f; } v; v.i = u << 16; return v.f;
}
__device__ __forceinline__ float bfhi2f(unsigned int u) {   // high bf16 -> f32
    union { unsigned int i; float f; } v; v.i = u & 0xffff0000u; return v.f;
}

// ---------------------------------------------------------------------------
// Prep: [blocks 0..2499] cast feat fp32 -> bf16 planes featb[2][NN][64]
//       [blocks 2500..2627] transpose+cast W to Wc[4][128][64]
//       [blocks 2628..2784] zero cnt[NN]
// ---------------------------------------------------------------------------
__global__ __launch_bounds__(256) void k_prep(
    const float* __restrict__ feat, const float* __restrict__ Wself,
    const float* __restrict__ Wneigh, unsigned short* __restrict__ featb,
    unsigned short* __restrict__ Wc, int* __restrict__ cnt)
{
    int b = blockIdx.x, t = threadIdx.x;
    if (b < 2500) {
        int idx8 = b * 256 + t;          // 640000 groups of 8 elements
        int n  = idx8 >> 4;              // 16 groups per row
        int d0 = (idx8 & 15) << 3;       // dim base 0,8,...,120
        const float4* fp =
            reinterpret_cast<const float4*>(feat + (size_t)n * DIM + d0);
        float4 v0 = fp[0], v1 = fp[1];
        unsigned int p0 = (unsigned int)f2bf(v0.x) | ((unsigned int)f2bf(v0.y) << 16);
        unsigned int p1 = (unsigned int)f2bf(v0.z) | ((unsigned int)f2bf(v0.w) << 16);
        unsigned int p2 = (unsigned int)f2bf(v1.x) | ((unsigned int)f2bf(v1.y) << 16);
        unsigned int p3 = (unsigned int)f2bf(v1.z) | ((unsigned int)f2bf(v1.w) << 16);
        int plane = d0 >> 6, off = d0 & 63;
        *reinterpret_cast<uint4*>(
            featb + (size_t)plane * PLANE + (size_t)n * 64 + off) =
            make_uint4(p0, p1, p2, p3);
    } else if (b < 2628) {
        int idx = (b - 2500) * 256 + t;  // 0..32767
        int c = idx >> 13, n = (idx >> 6) & 127, kp = idx & 63;
        int k = c * 64 + kp;
        float w = (k < DIM) ? Wself[(size_t)k * DIM + n]
                            : Wneigh[(size_t)(k - DIM) * DIM + n];
        Wc[idx] = f2bf(w);
    } else {
        int i = (b - 2628) * 256 + t;
        if (i < NN) cnt[i] = 0;
    }
}

// ---------------------------------------------------------------------------
// Adjacency fill, v3: XCD-partitioned dst ranges.
// r1 evidence: fused fill ran at 1 TB/s, VALU 1.3%, WRITE_SIZE 45MB vs ~14MB
// dirty data -> cross-XCD line ping-pong on scattered u16 stores + atomics.
// Fix: class r = blockIdx&7 (round-robin block->XCD) owns dst range
// [r*5000,(r+1)*5000): every cnt/colf line is written by ONE XCD only;
// 20KB cnt-slice + 0.48MB colf-slice stay L2-resident. Each class streams
// all edges (nontemporal so the 10MB stream doesn't evict the slices).
// ---------------------------------------------------------------------------
__global__ __launch_bounds__(256) void k_fill(
    const int* __restrict__ src, const int* __restrict__ dst,
    int* __restrict__ cnt, unsigned short* __restrict__ colf)
{
    int r  = blockIdx.x & 7;           // XCD class
    int bi = blockIdx.x >> 3;          // 0..79 within class
    int lo = r * 5000, hi = lo + 5000;
    const uint32x4* d4 = reinterpret_cast<const uint32x4*>(dst) + (size_t)bi * 2000;
    const uint32x4* s4 = reinterpret_cast<const uint32x4*>(src) + (size_t)bi * 2000;
    for (int it = threadIdx.x; it < 2000; it += 256) {
        uint32x4 dv = __builtin_nontemporal_load(d4 + it);
        uint32x4 sv = __builtin_nontemporal_load(s4 + it);
        #pragma unroll
        for (int k = 0; k < 4; ++k) {
            int d = (int)dv[k];
            if (d >= lo && d < hi) {
                int pos = atomicAdd(&cnt[d], 1);
                if (pos < CAP) colf[d * CAP + pos] = (unsigned short)sv[k];
            }
        }
    }
}

// ---------------------------------------------------------------------------
// Gather + mean over bf16 planes (UNCHANGED from r2 — frozen this round).
// One wave per node, lane covers 2 dims; 8 independent row loads in flight.
// ---------------------------------------------------------------------------
__global__ __launch_bounds__(256) void k_gather(
    const unsigned int* __restrict__ fb32,   // featb viewed as [2][NN][32] uint
    const int* __restrict__ cnt,
    const unsigned short* __restrict__ colf,
    unsigned int* __restrict__ hnb32)        // hnb viewed as [2][NN][32] uint
{
    int gtid = blockIdx.x * blockDim.x + threadIdx.x;
    int n = gtid >> 6;
    if (n >= NN) return;
    int lane = threadIdx.x & 63;

    int deg = cnt[n];
    int m = min(deg, CAP);
    int sv = (lane < m) ? (int)colf[n * CAP + lane] : 0;

    int vb = (lane >> 5) * (NN * 32) + (lane & 31);   // plane base + lane offset
    float ax0 = 0.f, ay0 = 0.f, ax1 = 0.f, ay1 = 0.f;
    int i = 0;
    for (; i + 7 < m; i += 8) {
        int s0 = __shfl(sv, i),     s1 = __shfl(sv, i + 1);
        int s2 = __shfl(sv, i + 2), s3 = __shfl(sv, i + 3);
        int s4 = __shfl(sv, i + 4), s5 = __shfl(sv, i + 5);
        int s6 = __shfl(sv, i + 6), s7 = __shfl(sv, i + 7);
        unsigned int u0 = fb32[vb + s0 * 32];
        unsigned int u1 = fb32[vb + s1 * 32];
        unsigned int u2 = fb32[vb + s2 * 32];
        unsigned int u3 = fb32[vb + s3 * 32];
        unsigned int u4 = fb32[vb + s4 * 32];
        unsigned int u5 = fb32[vb + s5 * 32];
        unsigned int u6 = fb32[vb + s6 * 32];
        unsigned int u7 = fb32[vb + s7 * 32];
        ax0 += bflo2f(u0); ay0 += bfhi2f(u0);
        ax1 += bflo2f(u1); ay1 += bfhi2f(u1);
        ax0 += bflo2f(u2); ay0 += bfhi2f(u2);
        ax1 += bflo2f(u3); ay1 += bfhi2f(u3);
        ax0 += bflo2f(u4); ay0 += bfhi2f(u4);
        ax1 += bflo2f(u5); ay1 += bfhi2f(u5);
        ax0 += bflo2f(u6); ay0 += bfhi2f(u6);
        ax1 += bflo2f(u7); ay1 += bfhi2f(u7);
    }
    for (; i + 3 < m; i += 4) {
        int s0 = __shfl(sv, i),     s1 = __shfl(sv, i + 1);
        int s2 = __shfl(sv, i + 2), s3 = __shfl(sv, i + 3);
        unsigned int u0 = fb32[vb + s0 * 32];
        unsigned int u1 = fb32[vb + s1 * 32];
        unsigned int u2 = fb32[vb + s2 * 32];
        unsigned int u3 = fb32[vb + s3 * 32];
        ax0 += bflo2f(u0); ay0 += bfhi2f(u0);
        ax1 += bflo2f(u1); ay1 += bfhi2f(u1);
        ax0 += bflo2f(u2); ay0 += bfhi2f(u2);
        ax1 += bflo2f(u3); ay1 += bfhi2f(u3);
    }
    for (; i < m; ++i) {
        int s0 = __shfl(sv, i);
        unsigned int u0 = fb32[vb + s0 * 32];
        ax0 += bflo2f(u0); ay0 += bfhi2f(u0);
    }
    float inv = 1.0f / fmaxf((float)deg, 1.0f);
    float ax = (ax0 + ax1) * inv, ay = (ay0 + ay1) * inv;
    hnb32[vb + n * 32] = (unsigned int)f2bf(ax) | ((unsigned int)f2bf(ay) << 16);
}

// ---------------------------------------------------------------------------
// Fused GEMM: out[40000x128] = [featb | hnb] (K=256 bf16) @ Wc + biases.
// v3: T2 XOR-swizzle on LDS (both-sides rule 21): LDS dest stays linear for
// global_load_lds; SOURCE address is inverse-swizzled (g_src = g_lds ^ (row&7),
// 16B granules inside each 128B row -> coalescing preserved); reads apply the
// same XOR. Kills the 16-way ds_read_b128 bank conflict (stride-128B rows).
// ---------------------------------------------------------------------------
__global__ __launch_bounds__(320) void k_gemm(
    const unsigned short* __restrict__ featb,  // [2][NN][64]
    const unsigned short* __restrict__ hnb,    // [2][NN][64]
    const unsigned short* __restrict__ Wc,     // [4][128][64]
    const float* __restrict__ bself, const float* __restrict__ bneigh,
    float* __restrict__ out)                   // [NN,128] fp32
{
    __shared__ unsigned short As[160 * 64];  // 20480 B
    __shared__ unsigned short Bs[128 * 64];  // 16384 B

    int t = threadIdx.x;
    int w = t >> 6;
    int lane = t & 63;
    int base_m = blockIdx.x * 160;

    floatx4 acc[2][8];
    #pragma unroll
    for (int a = 0; a < 2; ++a)
        #pragma unroll
        for (int b = 0; b < 8; ++b) acc[a][b] = (floatx4)0.f;

    for (int c = 0; c < 4; ++c) {
        // ---- stage A chunk (20480 B): plane c of featb (c<2) or hnb ----
        const unsigned short* srcp =
            ((c < 2) ? featb + (size_t)c * PLANE
                     : hnb + (size_t)(c - 2) * PLANE) + (size_t)base_m * 64;
        #pragma unroll
        for (int it = 0; it < 4; ++it) {          // 1280 slots / 320 threads
            int s = t + it * 320;
            int m = s >> 3, g = s & 7;            // LDS (row m, 16B-granule g)
            const unsigned short* sa = srcp + m * 64 + ((g ^ (m & 7)) << 3);
            __builtin_amdgcn_global_load_lds(
                (const __attribute__((address_space(1))) unsigned int*)sa,
                (__attribute__((address_space(3))) unsigned int*)(As + s * 8),
                16, 0, 0);
        }
        // ---- stage B chunk (16384 B): waves 0..3 ----
        if (t < 256) {
            const unsigned short* bp = Wc + (size_t)c * 128 * 64;
            #pragma unroll
            for (int it = 0; it < 4; ++it) {      // 1024 slots / 256 threads
                int s = t + it * 256;
                int n = s >> 3, g = s & 7;
                const unsigned short* sb = bp + n * 64 + ((g ^ (n & 7)) << 3);
                __builtin_amdgcn_global_load_lds(
                    (const __attribute__((address_space(1))) unsigned int*)sb,
                    (__attribute__((address_space(3))) unsigned int*)(Bs + s * 8),
                    16, 0, 0);
            }
        }
        __syncthreads();

        // ---- 2 k-steps of 32 ----
        #pragma unroll
        for (int sstep = 0; sstep < 2; ++sstep) {
            int gk = sstep * 4 + (lane >> 4);     // source 16B-granule wanted
            short8 af[2];
            #pragma unroll
            for (int mt = 0; mt < 2; ++mt) {
                int m = w * 32 + mt * 16 + (lane & 15);
                af[mt] = *reinterpret_cast<const short8*>(
                    As + m * 64 + ((gk ^ (m & 7)) << 3));
            }
            #pragma unroll
            for (int nt = 0; nt < 8; ++nt) {
                int n = nt * 16 + (lane & 15);
                short8 bf = *reinterpret_cast<const short8*>(
                    Bs + n * 64 + ((gk ^ (n & 7)) << 3));
                acc[0][nt] = __builtin_amdgcn_mfma_f32_16x16x32_bf16(
                    af[0], bf, acc[0][nt], 0, 0, 0);
                acc[1][nt] = __builtin_amdgcn_mfma_f32_16x16x32_bf16(
                    af[1], bf, acc[1][nt], 0, 0, 0);
            }
        }
        __syncthreads();
    }

    // ---- epilogue: C/D layout col=lane&15, row=(lane>>4)*4+reg ----
    int colb = lane & 15;
    int quad = lane >> 4;
    #pragma unroll
    for (int nt = 0; nt < 8; ++nt) {
        int col = nt * 16 + colb;
        float bb = bself[col] + bneigh[col];
        #pragma unroll
        for (int mt = 0; mt < 2; ++mt) {
            #pragma unroll
            for (int r = 0; r < 4; ++r) {
                int row = base_m + w * 32 + mt * 16 + quad * 4 + r;
                out[(size_t)row * DIM + col] = acc[mt][nt][r] + bb;
            }
        }
    }
}

// ---------------------------------------------------------------------------
extern "C" void kernel_launch(void* const* d_in, const int* in_sizes, int n_in,
                              void* d_out, int out_size, void* d_ws, size_t ws_size,
                              hipStream_t stream)
{
    const float* feat   = (const float*)d_in[0];
    const int*   src    = (const int*)d_in[1];
    const int*   dst    = (const int*)d_in[2];
    const float* Wself  = (const float*)d_in[3];
    const float* bself  = (const float*)d_in[4];
    const float* Wneigh = (const float*)d_in[5];
    const float* bneigh = (const float*)d_in[6];
    float* out = (float*)d_out;

    // Workspace layout (bytes):
    //   featb [2][NN][64] bf16 @ 0           (10,240,000)
    //   hnb   [2][NN][64] bf16 @ 10,240,000  (10,240,000)
    //   colf  [NN][CAP]   u16  @ 20,480,000  ( 3,840,000)
    //   Wc    [4][128][64]bf16 @ 24,320,000  (    65,536)
    //   cnt   [NN]        i32  @ 24,385,536  (   160,000)
    // total 24,545,536 B
    char* ws = (char*)d_ws;
    unsigned short* featb = (unsigned short*)(ws);
    unsigned short* hnb   = (unsigned short*)(ws + 10240000);
    unsigned short* colf  = (unsigned short*)(ws + 20480000);
    unsigned short* Wc    = (unsigned short*)(ws + 24320000);
    int*            cnt   = (int*)(ws + 24385536);

    k_prep<<<2785, 256, 0, stream>>>(feat, Wself, Wneigh, featb, Wc, cnt);

    k_fill<<<640, 256, 0, stream>>>(src, dst, cnt, colf);

    k_gather<<<(NN * 64) / 256, 256, 0, stream>>>(
        (const unsigned int*)featb, cnt, colf, (unsigned int*)hnb);

    k_gemm<<<NN / 160, 320, 0, stream>>>(featb, hnb, Wc, bself, bneigh, out);
}